// Round 8
// baseline (530.605 us; speedup 1.0000x reference)
//
#include <hip/hip_runtime.h>
#include <stdint.h>

// Problem constants
#define FD 1024          // feature dim (K)
#define NC 8192          // classes per view
#define NT 16384         // N = 2*NC
#define NKT 16           // K-tiles of 64

typedef __attribute__((ext_vector_type(8))) short bf16x8;
typedef __attribute__((ext_vector_type(4))) float f32x4;

__device__ __forceinline__ unsigned short f2bf(float f) {
  unsigned u = __float_as_uint(f);
  u += 0x7FFF + ((u >> 16) & 1);   // RNE
  return (unsigned short)(u >> 16);
}
__device__ __forceinline__ float bf2f(unsigned short s) {
  return __uint_as_float(((unsigned)s) << 16);
}

// async global->LDS, 16B/lane; LDS dest wave-uniform (HW adds lane*16)
__device__ __forceinline__ void gld16(const void* g, void* l) {
  __builtin_amdgcn_global_load_lds(
      (const __attribute__((address_space(1))) unsigned int*)g,
      (__attribute__((address_space(3))) unsigned int*)l, 16, 0, 0);
}

// online-LSE merge of (m2,s2) into packed global state {lo: m bits, hi: s bits}
__device__ __forceinline__ void cas_merge(unsigned long long* p, float m2, float s2) {
  unsigned long long old = *p, assumed;
  do {
    assumed = old;
    float m1 = __uint_as_float((unsigned)(assumed & 0xffffffffull));
    float s1 = __uint_as_float((unsigned)(assumed >> 32));
    float mn = fmaxf(m1, m2);                       // m2 always finite
    float s = s1 * __expf(m1 - mn) + s2 * __expf(m2 - mn);
    unsigned long long nv =
        ((unsigned long long)__float_as_uint(s) << 32) | __float_as_uint(mn);
    old = atomicCAS(p, assumed, nv);
  } while (old != assumed);
}

// per-XCD supertiled triangle decode (4x4-tile supertiles on 16x16 supergrid)
__device__ __forceinline__ void decode_tile(int xcd, int p, int& ti, int& tj) {
  if (p < 20) {
    const int hi = (p >= 10) ? 1 : 0;
    const int d = 2 * xcd + hi;
    const int q = p - hi * 10;                 // 0..9 in 4x4 triangle
    int i = 0;
    while ((i + 1) * 4 - ((i + 1) * i) / 2 <= q) ++i;
    const int j = i + (q - (i * 4 - (i * (i - 1)) / 2));
    ti = d * 4 + i; tj = d * 4 + j;
  } else {
    const int t = p - 20;                      // 0..239
    const int o = 15 * xcd + (t >> 4);         // 0..119 strict-upper index
    const int q = t & 15;
    int SI = 0;
    while (15 * (SI + 1) - ((SI + 1) * SI) / 2 <= o) ++SI;
    const int SJ = SI + 1 + (o - (15 * SI - (SI * (SI - 1)) / 2));
    ti = SI * 4 + (q >> 2); tj = SJ * 4 + (q & 3);
  }
}

// ---------------------------------------------------------------------------
__global__ void nt_xent_init(unsigned long long* __restrict__ G) {
  G[blockIdx.x * 256 + threadIdx.x] = 0xFF800000ull;  // m=-inf, s=0
}

// ---------------------------------------------------------------------------
// Kernel T: h_i,h_j [1024][8192] fp32 -> HT [16384][1024] bf16 (transposed)
// ---------------------------------------------------------------------------
__global__ void nt_xent_transpose(const float* __restrict__ hi,
                                  const float* __restrict__ hj,
                                  unsigned short* __restrict__ HT) {
  __shared__ unsigned short tile[64][65];
  const int bn = blockIdx.x, bd = blockIdx.y;
  const int n0 = bn * 64, d0 = bd * 64;
  const float* src = (n0 < NC) ? hi : hj;
  const int nb = (n0 < NC) ? n0 : n0 - NC;
  const int tid = threadIdx.x;
#pragma unroll
  for (int i = 0; i < 16; ++i) {
    int idx = tid + 256 * i;
    int dl = idx >> 6, nl = idx & 63;
    float f = src[(size_t)(d0 + dl) * NC + nb + nl];
    tile[nl][dl] = f2bf(f);
  }
  __syncthreads();
#pragma unroll
  for (int i = 0; i < 16; ++i) {
    int idx = tid + 256 * i;
    int nl = idx >> 6, dl = idx & 63;
    HT[(size_t)(n0 + nl) * FD + d0 + dl] = tile[nl][dl];
  }
}

// ---------------------------------------------------------------------------
// Kernel G: PERSISTENT 256x256-tile symmetric SYRK, 4-phase K-tiles with
//   counted vmcnt(4) + setprio. R7 change vs R6 (single variable):
//   NO sched_barrier(0), NO forced lgkmcnt(0) in the phase loop — the
//   ds_reads are compiler-visible, so hipcc inserts exact lgkmcnt(N) and
//   may interleave reads/MFMAs within a phase (m141: pinning cost −42%).
//   Raw s_barrier pairs + the two vmcnt(4) landing guarantees remain.
// ---------------------------------------------------------------------------
__global__ __launch_bounds__(512, 1)
void nt_xent_gemm_lse(const unsigned short* __restrict__ HT,
                      unsigned long long* __restrict__ G) {
  __shared__ __align__(16) unsigned char lds[143360];

  const int tid = threadIdx.x;
  const int w = tid >> 6, l = tid & 63;
  const int lr = l & 15;
  const int lk = (l >> 4) * 8;
  const int wr = w >> 2, wc = w & 3;

  const int xcd = blockIdx.x & 7;
  const int slot = blockIdx.x >> 3;      // 0..31

// stage both frags of one group for a K-tile: dst buf DBUF, k-half KK, A/B ISB
#define STAGE2(AB, BB, KO, DBUF, KK, ISB) do {                               \
    const unsigned short* _s = (ISB) ? (BB) : (AB);                          \
    unsigned char* _d = lds + (DBUF) * 65536 + (ISB) * 32768 +               \
                        (KK) * 16384 + (2 * w) * 1024;                       \
    const int _ko = (KO) + (KK) * 32 + lk;                                   \
    gld16(_s + (((size_t)(2 * w * 16 + lr)) << 10) + _ko, _d);               \
    gld16(_s + (((size_t)((2 * w + 1) * 16 + lr)) << 10) + _ko, _d + 1024);  \
  } while (0)

#define RDA(BUF, KK, MI) \
  (*(const bf16x8*)(lds + (BUF) * 65536 + (KK) * 16384 + (wr * 8 + (MI)) * 1024 + l * 16))
#define RDB(BUF, KK, N) \
  (*(const bf16x8*)(lds + (BUF) * 65536 + 32768 + (KK) * 16384 + (wc * 4 + (N)) * 1024 + l * 16))

#define MFMA16(MB)                                                           \
  _Pragma("unroll") for (int m = 0; m < 4; ++m)                              \
  _Pragma("unroll") for (int n = 0; n < 4; ++n)                              \
    acc[(MB) + m][n] = __builtin_amdgcn_mfma_f32_16x16x32_bf16(              \
        av[m], bv[n], acc[(MB) + m][n], 0, 0, 0);

#define VM4 asm volatile("s_waitcnt vmcnt(4)" ::: "memory")

// one K-tile (buffer BUF), staging the FOLLOWING K-tile (bases NA/NB, k-off NKO)
#define KTILE(BUF, NA, NB, NKO) do {                                         \
    bv[0] = RDB(BUF, 0, 0); bv[1] = RDB(BUF, 0, 1);                          \
    bv[2] = RDB(BUF, 0, 2); bv[3] = RDB(BUF, 0, 3);                          \
    av[0] = RDA(BUF, 0, 0); av[1] = RDA(BUF, 0, 1);                          \
    av[2] = RDA(BUF, 0, 2); av[3] = RDA(BUF, 0, 3);                          \
    STAGE2(NA, NB, NKO, (BUF) ^ 1, 0, 0);                                    \
    __builtin_amdgcn_s_barrier();                                            \
    __builtin_amdgcn_s_setprio(1); MFMA16(0) __builtin_amdgcn_s_setprio(0);  \
    __builtin_amdgcn_s_barrier();                                            \
    av[0] = RDA(BUF, 0, 4); av[1] = RDA(BUF, 0, 5);                          \
    av[2] = RDA(BUF, 0, 6); av[3] = RDA(BUF, 0, 7);                          \
    STAGE2(NA, NB, NKO, (BUF) ^ 1, 0, 1);                                    \
    VM4;                                                                     \
    __builtin_amdgcn_s_barrier();                                            \
    __builtin_amdgcn_s_setprio(1); MFMA16(4) __builtin_amdgcn_s_setprio(0);  \
    __builtin_amdgcn_s_barrier();                                            \
    bv[0] = RDB(BUF, 1, 0); bv[1] = RDB(BUF, 1, 1);                          \
    bv[2] = RDB(BUF, 1, 2); bv[3] = RDB(BUF, 1, 3);                          \
    av[0] = RDA(BUF, 1, 0); av[1] = RDA(BUF, 1, 1);                          \
    av[2] = RDA(BUF, 1, 2); av[3] = RDA(BUF, 1, 3);                          \
    STAGE2(NA, NB, NKO, (BUF) ^ 1, 1, 0);                                    \
    __builtin_amdgcn_s_barrier();                                            \
    __builtin_amdgcn_s_setprio(1); MFMA16(0) __builtin_amdgcn_s_setprio(0);  \
    __builtin_amdgcn_s_barrier();                                            \
    av[0] = RDA(BUF, 1, 4); av[1] = RDA(BUF, 1, 5);                          \
    av[2] = RDA(BUF, 1, 6); av[3] = RDA(BUF, 1, 7);                          \
    STAGE2(NA, NB, NKO, (BUF) ^ 1, 1, 1);                                    \
    VM4;                                                                     \
    __builtin_amdgcn_s_barrier();                                            \
    __builtin_amdgcn_s_setprio(1); MFMA16(4) __builtin_amdgcn_s_setprio(0);  \
    __builtin_amdgcn_s_barrier();                                            \
  } while (0)

  f32x4 acc[8][4];
#pragma unroll
  for (int a = 0; a < 8; ++a)
#pragma unroll
    for (int b = 0; b < 4; ++b) acc[a][b] = (f32x4){0.f, 0.f, 0.f, 0.f};
  bf16x8 av[4], bv[4];

  // ---- first tile + prologue: stage its K-tile 0 into buf0, full wait ----
  int p = slot, ti, tj;
  decode_tile(xcd, p, ti, tj);
  const unsigned short* Acur = HT + (((size_t)ti) << 18);
  const unsigned short* Bcur = HT + (((size_t)tj) << 18);
  STAGE2(Acur, Bcur, 0, 0, 0, 0);
  STAGE2(Acur, Bcur, 0, 0, 0, 1);
  STAGE2(Acur, Bcur, 0, 0, 1, 0);
  STAGE2(Acur, Bcur, 0, 0, 1, 1);
  asm volatile("s_waitcnt vmcnt(0)" ::: "memory");
  __builtin_amdgcn_s_barrier();

  while (true) {
    // pre-decode next tile (dummy = tile(0,0): valid addresses, never read)
    const int pn = p + 32;
    const bool has_next = (pn < 260);
    int tin = 0, tjn = 0;
    if (has_next) decode_tile(xcd, pn, tin, tjn);
    const unsigned short* Anx = HT + (((size_t)tin) << 18);
    const unsigned short* Bnx = HT + (((size_t)tjn) << 18);

    // ---- 16 K-tiles; T=0..14 stage same tile, T=15 stages next tile K0 ----
#pragma unroll 1
    for (int Tp = 0; Tp < 7; ++Tp) {
      KTILE(0, Acur, Bcur, (2 * Tp + 1) * 64);
      KTILE(1, Acur, Bcur, (2 * Tp + 2) * 64);
    }
    KTILE(0, Acur, Bcur, 15 * 64);
    KTILE(1, Anx, Bnx, 0);

    // ---- epilogue in spare LDS (no pipeline drain) ----
    {
      float (*red)[4][128][2] = (float (*)[4][128][2])(lds + 131072);
      float (*redc)[2][64][2] = (float (*)[2][64][2])(lds + 139264);
      const int gr0 = ti * 256 + wr * 128 + ((l >> 4) << 2);
      const int gc0 = tj * 256 + wc * 64 + lr;
#pragma unroll
      for (int m = 0; m < 8; ++m) {
#pragma unroll
        for (int rg = 0; rg < 4; ++rg) {
          const int grow = gr0 + m * 16 + rg;
          float vs[4];
          float mx = -INFINITY;
#pragma unroll
          for (int n = 0; n < 4; ++n) {
            float v = acc[m][n][rg] * 2.0f;            // 1/T = 2
            if (gc0 + n * 16 == grow) v = -INFINITY;   // mask diagonal
            vs[n] = v;
            mx = fmaxf(mx, v);
          }
#pragma unroll
          for (int off = 1; off < 16; off <<= 1) mx = fmaxf(mx, __shfl_xor(mx, off, 16));
          float sm = 0.f;
#pragma unroll
          for (int n = 0; n < 4; ++n) sm += __expf(vs[n] - mx);
#pragma unroll
          for (int off = 1; off < 16; off <<= 1) sm += __shfl_xor(sm, off, 16);
          if (lr == 0) {
            const int rl = m * 16 + ((l >> 4) << 2) + rg;   // 0..127
            red[wr][wc][rl][0] = mx;
            red[wr][wc][rl][1] = sm;
          }
        }
      }
      if (ti != tj) {
#pragma unroll
        for (int n = 0; n < 4; ++n) {
          float mx = -INFINITY;
#pragma unroll
          for (int m = 0; m < 8; ++m)
#pragma unroll
            for (int rg = 0; rg < 4; ++rg) mx = fmaxf(mx, acc[m][n][rg] * 2.0f);
          mx = fmaxf(mx, __shfl_xor(mx, 16));
          mx = fmaxf(mx, __shfl_xor(mx, 32));
          float sm = 0.f;
#pragma unroll
          for (int m = 0; m < 8; ++m)
#pragma unroll
            for (int rg = 0; rg < 4; ++rg) sm += __expf(acc[m][n][rg] * 2.0f - mx);
          sm += __shfl_xor(sm, 16);
          sm += __shfl_xor(sm, 32);
          if (l < 16) {
            redc[wc][wr][n * 16 + lr][0] = mx;
            redc[wc][wr][n * 16 + lr][1] = sm;
          }
        }
      }
      // reset accumulators for next tile
#pragma unroll
      for (int a = 0; a < 8; ++a)
#pragma unroll
        for (int b = 0; b < 4; ++b) acc[a][b] = (f32x4){0.f, 0.f, 0.f, 0.f};

      asm volatile("s_waitcnt lgkmcnt(0)" ::: "memory");
      __builtin_amdgcn_s_barrier();

      if (tid < 256) {
        const int row = tid, wrr = row >> 7, rl = row & 127;
        float M = -INFINITY;
#pragma unroll
        for (int c = 0; c < 4; ++c) M = fmaxf(M, red[wrr][c][rl][0]);
        float S = 0.f;
#pragma unroll
        for (int c = 0; c < 4; ++c) S += red[wrr][c][rl][1] * __expf(red[wrr][c][rl][0] - M);
        cas_merge(&G[ti * 256 + row], M, S);
      } else if (ti != tj) {
        const int col = tid - 256, wcc = col >> 6, cl = col & 63;
        float m0 = redc[wcc][0][cl][0], s0 = redc[wcc][0][cl][1];
        float m1 = redc[wcc][1][cl][0], s1 = redc[wcc][1][cl][1];
        float mn = fmaxf(m0, m1);
        float s = s0 * __expf(m0 - mn) + s1 * __expf(m1 - mn);
        cas_merge(&G[tj * 256 + col], mn, s);
      }
      __builtin_amdgcn_s_barrier();
    }

    if (!has_next) break;
    p = pn; ti = tin; tj = tjn; Acur = Anx; Bcur = Bnx;
  }

#undef STAGE2
#undef RDA
#undef RDB
#undef MFMA16
#undef VM4
#undef KTILE
}

// ---------------------------------------------------------------------------
// Kernel F: lse[i] = m + log(s); pos = 2*dot(HT[i],HT[partner]);
//           out += (lse - pos)/NT
// ---------------------------------------------------------------------------
__global__ void nt_xent_final(const unsigned short* __restrict__ HT,
                              const unsigned long long* __restrict__ G,
                              float* __restrict__ out) {
  const int tid = threadIdx.x;
  const int w = tid >> 6, l = tid & 63;
  const int wave = blockIdx.x * 4 + w;      // 0..1023, 16 rows each
  float local = 0.f;
  for (int rr = 0; rr < 16; ++rr) {
    int i = wave * 16 + rr;
    int p = (i + NC) & (NT - 1);
    const int4* A = (const int4*)(HT + (((size_t)i) << 10) + (l << 4));
    const int4* B = (const int4*)(HT + (((size_t)p) << 10) + (l << 4));
    union { int4 v; unsigned short u[8]; } a0, a1, b0, b1;
    a0.v = A[0]; a1.v = A[1]; b0.v = B[0]; b1.v = B[1];
    float dot = 0.f;
#pragma unroll
    for (int j = 0; j < 8; ++j) dot += bf2f(a0.u[j]) * bf2f(b0.u[j]);
#pragma unroll
    for (int j = 0; j < 8; ++j) dot += bf2f(a1.u[j]) * bf2f(b1.u[j]);
#pragma unroll
    for (int off = 1; off < 64; off <<= 1) dot += __shfl_xor(dot, off, 64);
    if (l == 0) {
      unsigned long long g = G[i];
      float m = __uint_as_float((unsigned)(g & 0xffffffffull));
      float s = __uint_as_float((unsigned)(g >> 32));
      local += m + __logf(s) - 2.0f * dot;
    }
  }
  if (l == 0) atomicAdd(out, local * (1.0f / (float)NT));
}

// ---------------------------------------------------------------------------
extern "C" void kernel_launch(void* const* d_in, const int* in_sizes, int n_in,
                              void* d_out, int out_size, void* d_ws, size_t ws_size,
                              hipStream_t stream) {
  const float* hi = (const float*)d_in[0];
  const float* hj = (const float*)d_in[1];
  unsigned short* HT = (unsigned short*)d_ws;
  unsigned long long* G = (unsigned long long*)((char*)d_ws + (size_t)NT * FD * 2);
  float* out = (float*)d_out;

  const size_t need = (size_t)NT * FD * 2 + (size_t)NT * 8;
  if (ws_size < need) return;

  hipMemsetAsync(out, 0, sizeof(float), stream);
  nt_xent_init<<<NT / 256, 256, 0, stream>>>(G);
  nt_xent_transpose<<<dim3(NT / 64, FD / 64), 256, 0, stream>>>(hi, hj, HT);
  nt_xent_gemm_lse<<<256, 512, 0, stream>>>(HT, G);
  nt_xent_final<<<NT / 64, 256, 0, stream>>>(HT, G, out);
}